// Round 7
// baseline (409.668 us; speedup 1.0000x reference)
//
#include <hip/hip_runtime.h>
#include <stdint.h>

typedef __bf16 bf16;
typedef __bf16 bf16x4 __attribute__((ext_vector_type(4)));
typedef __bf16 bf16x8 __attribute__((ext_vector_type(8)));
typedef float f32x4 __attribute__((ext_vector_type(4)));

#define CN 524288    // C*N = 512*1024 (per-batch x elements)
#define NPIX 1024
#define CCH 512

// ---- async global->LDS, 16B per lane ----
__device__ __forceinline__ void gload_lds16(const void* g, void* l) {
  auto gp = reinterpret_cast<const __attribute__((address_space(1))) uint32_t*>(
      reinterpret_cast<uintptr_t>(g));
  auto lp = reinterpret_cast<__attribute__((address_space(3))) uint32_t*>(
      static_cast<uint32_t>(reinterpret_cast<uintptr_t>(l)));
  __builtin_amdgcn_global_load_lds(gp, lp, 16, 0, 0);
}

// ======================================================================
// gemm_bt (r2-verified engine): C[i,j] = sum_k A[i,k] * Bt[j,k]
// 128x128 tile, BK=64, 4 waves (64x64 each), 16x16x32 bf16 MFMA.
// Verified seg-XOR swizzle (0 bank conflicts on HW).
// EPI 0: QKV   (bias; j<1024 -> qkT[i][j], else v[j-1024][i])
// EPI 1: scores (fp32 out * scale) + per-(block,wavecol) partial softmax
//        stats (row max + expsum over the wave's 64 cols x 2 wc) -> pst
// EPI 3: proj  (fp32 out + proj_b[i] + resid)
// ======================================================================
template<int EPI>
__global__ __launch_bounds__(256)
void gemm_bt(const bf16* __restrict__ A, int lda, long long sA,
             const bf16* __restrict__ Bt, int ldb, long long sB,
             char* __restrict__ Cp, long long sC,
             char* __restrict__ C2p, long long sC2,
             const float* __restrict__ bias,
             const float* __restrict__ resid,
             float* __restrict__ pst,
             int K, float scale)
{
  __shared__ __align__(16) bf16 As[128 * 64];
  __shared__ __align__(16) bf16 Bs[128 * 64];
  const int t = threadIdx.x;
  const int w = t >> 6;
  const int l = t & 63;
  const int z = blockIdx.z;
  A  += (long long)z * sA;
  Bt += (long long)z * sB;
  Cp += (long long)z * sC;
  if (C2p) C2p += (long long)z * sC2;
  const float* residb = (EPI == 3) ? (resid + (long long)z * CN) : nullptr;

  const int row0 = blockIdx.x * 128;
  const int col0 = blockIdx.y * 128;
  const int wr = (w >> 1) * 64;
  const int wc = (w & 1) * 64;

  f32x4 acc[4][4] = {};

  const int srow = t >> 3;            // 0..31: row within 32-row staging chunk
  const int sseg = l & 7;             // 16B segment within 128B row (pre-swizzle)
  const int lrow = l & 15;
  const int lseg = l >> 4;            // 0..3

  for (int k0 = 0; k0 < K; k0 += 64) {
    #pragma unroll
    for (int li = 0; li < 4; ++li) {
      const int row = li * 32 + srow;
      const int kofs = k0 + ((sseg ^ (row & 7)) << 3);
      const bf16* ga = A  + (long long)(row0 + row) * lda + kofs;
      const bf16* gb = Bt + (long long)(col0 + row) * ldb + kofs;
      gload_lds16(ga, &As[li * 2048 + w * 512]);   // wave-uniform LDS base
      gload_lds16(gb, &Bs[li * 2048 + w * 512]);
    }
    __syncthreads();   // compiler drains vmcnt(0) before s_barrier
    #pragma unroll
    for (int kk = 0; kk < 2; ++kk) {
      bf16x8 af[4], bfr[4];
      #pragma unroll
      for (int m = 0; m < 4; ++m) {
        const int r = wr + m * 16 + lrow;
        const int sg = ((kk * 4 + lseg) ^ (r & 7)) * 8;
        af[m] = *(const bf16x8*)&As[r * 64 + sg];
      }
      #pragma unroll
      for (int n = 0; n < 4; ++n) {
        const int r = wc + n * 16 + lrow;
        const int sg = ((kk * 4 + lseg) ^ (r & 7)) * 8;
        bfr[n] = *(const bf16x8*)&Bs[r * 64 + sg];
      }
      #pragma unroll
      for (int m = 0; m < 4; ++m)
        #pragma unroll
        for (int n = 0; n < 4; ++n)
          acc[m][n] = __builtin_amdgcn_mfma_f32_16x16x32_bf16(af[m], bfr[n], acc[m][n], 0, 0, 0);
    }
    __syncthreads();
  }

  (void)scale;
  const int ci = (l >> 4) * 4;
  const int cj = l & 15;
  #pragma unroll
  for (int m = 0; m < 4; ++m) {
    const int i0 = row0 + wr + m * 16 + ci;
    #pragma unroll
    for (int n = 0; n < 4; ++n) {
      const int j = col0 + wc + n * 16 + cj;
      const f32x4 a = acc[m][n];
      if constexpr (EPI == 0) {
        const float bj = bias[j];
        if (j < NPIX) {
          bf16* q = (bf16*)Cp;
          #pragma unroll
          for (int r = 0; r < 4; ++r)
            q[(i0 + r) * NPIX + j] = (bf16)(a[r] + bj);
        } else {
          bf16* vb = (bf16*)C2p;
          #pragma unroll
          for (int r = 0; r < 4; ++r)
            vb[(j - NPIX) * NPIX + (i0 + r)] = (bf16)(a[r] + bj);
        }
      } else if constexpr (EPI == 1) {
        float* sp = (float*)Cp;
        #pragma unroll
        for (int r = 0; r < 4; ++r)
          sp[(i0 + r) * NPIX + j] = a[r] * scale;
      } else {
        float* op = (float*)Cp;
        #pragma unroll
        for (int r = 0; r < 4; ++r)
          op[(i0 + r) * NPIX + j] = a[r] + bias[i0 + r] + residb[(i0 + r) * NPIX + j];
      }
    }
  }

  // ---- EPI1: partial softmax stats over this wave's 64 cols ----
  if constexpr (EPI == 1) {
    float* pbase = pst + (((long long)z * 8 + blockIdx.y) * 2 + (w & 1)) * 2048;
    #pragma unroll
    for (int m = 0; m < 4; ++m) {
      #pragma unroll
      for (int r = 0; r < 4; ++r) {
        float mx = fmaxf(fmaxf(acc[m][0][r], acc[m][1][r]),
                         fmaxf(acc[m][2][r], acc[m][3][r])) * scale;
        #pragma unroll
        for (int off = 1; off < 16; off <<= 1) mx = fmaxf(mx, __shfl_xor(mx, off));
        float sm = 0.f;
        #pragma unroll
        for (int n = 0; n < 4; ++n) sm += __expf(acc[m][n][r] * scale - mx);
        #pragma unroll
        for (int off = 1; off < 16; off <<= 1) sm += __shfl_xor(sm, off);
        if ((l & 15) == 0) {
          const int nrow = row0 + wr + m * 16 + ci + r;   // 0..1023 batch-local
          pbase[nrow] = mx;
          pbase[1024 + nrow] = sm;
        }
      }
    }
  }
}

// ======================================================================
// pv_fused: hvT[n][c] = sum_m softmax(S)[n][m] * v[c][m]
// r2 gemm skeleton; A (=P) staged by reading S fp32 (L3-resident),
// applying exp(s - mx) * inv_sum in-register, ds_write_b128 bf16 with the
// same seg-XOR swizzle. B (=v) staged via verified gload_lds path.
// Row stats combined from 16 partials (8 mblk x 2 wc) in the prologue.
// ======================================================================
__global__ __launch_bounds__(256)
void pv_fused(const float* __restrict__ S, long long sS,
              const float* __restrict__ pst, long long sP,
              const bf16* __restrict__ V, long long sV,
              bf16* __restrict__ H, long long sH)
{
  __shared__ __align__(16) bf16 As[128 * 64];
  __shared__ __align__(16) bf16 Bs[128 * 64];
  const int t = threadIdx.x;
  const int w = t >> 6;
  const int l = t & 63;
  const int z = blockIdx.z;
  S   += (long long)z * sS;
  pst += (long long)z * sP;
  V   += (long long)z * sV;
  H   += (long long)z * sH;
  const int row0 = blockIdx.x * 128;   // n
  const int col0 = blockIdx.y * 128;   // c

  // ---- combine partial stats for this thread's staging row ----
  const int an  = t >> 1;              // 0..127 tile-local row
  const int myn = row0 + an;
  float mx = -3.4e38f;
  #pragma unroll
  for (int i = 0; i < 16; ++i) mx = fmaxf(mx, pst[i * 2048 + myn]);
  float sum = 0.f;
  #pragma unroll
  for (int i = 0; i < 16; ++i)
    sum += pst[i * 2048 + 1024 + myn] * __expf(pst[i * 2048 + myn] - mx);
  const float isum = 1.f / sum;

  const int amh = (t & 1) * 32;        // m-offset within K-tile
  const float* Srow = S + (long long)myn * 1024 + amh;

  const int srow = t >> 3;
  const int sseg = l & 7;
  const int wr = (w >> 1) * 64;
  const int wc = (w & 1) * 64;
  const int lrow = l & 15;
  const int lseg = l >> 4;

  f32x4 acc[4][4] = {};

  for (int k0 = 0; k0 < 1024; k0 += 64) {
    // issue fp32 S loads early
    float4 sv[8];
    #pragma unroll
    for (int q = 0; q < 8; ++q)
      sv[q] = *(const float4*)(Srow + k0 + q * 4);
    // B staging (v) via gload_lds, verified swizzle
    #pragma unroll
    for (int li = 0; li < 4; ++li) {
      const int rowb = li * 32 + srow;
      const int kofs = k0 + ((sseg ^ (rowb & 7)) << 3);
      gload_lds16(V + (long long)(col0 + rowb) * 1024 + kofs,
                  &Bs[li * 2048 + w * 512]);
    }
    // A: exp + normalize -> bf16, swizzled ds_write
    #pragma unroll
    for (int q = 0; q < 4; ++q) {
      const float4 a0 = sv[2 * q], a1 = sv[2 * q + 1];
      bf16x8 pw;
      pw[0] = (bf16)(__expf(a0.x - mx) * isum);
      pw[1] = (bf16)(__expf(a0.y - mx) * isum);
      pw[2] = (bf16)(__expf(a0.z - mx) * isum);
      pw[3] = (bf16)(__expf(a0.w - mx) * isum);
      pw[4] = (bf16)(__expf(a1.x - mx) * isum);
      pw[5] = (bf16)(__expf(a1.y - mx) * isum);
      pw[6] = (bf16)(__expf(a1.z - mx) * isum);
      pw[7] = (bf16)(__expf(a1.w - mx) * isum);
      const int sg = (((amh >> 3) + q) ^ (an & 7));
      *(bf16x8*)&As[an * 64 + sg * 8] = pw;
    }
    __syncthreads();   // drains lgkm (ds_write) + vm (gload_lds)
    #pragma unroll
    for (int kk = 0; kk < 2; ++kk) {
      bf16x8 af[4], bfr[4];
      #pragma unroll
      for (int m = 0; m < 4; ++m) {
        const int r = wr + m * 16 + lrow;
        const int sg = ((kk * 4 + lseg) ^ (r & 7)) * 8;
        af[m] = *(const bf16x8*)&As[r * 64 + sg];
      }
      #pragma unroll
      for (int n = 0; n < 4; ++n) {
        const int r = wc + n * 16 + lrow;
        const int sg = ((kk * 4 + lseg) ^ (r & 7)) * 8;
        bfr[n] = *(const bf16x8*)&Bs[r * 64 + sg];
      }
      #pragma unroll
      for (int m = 0; m < 4; ++m)
        #pragma unroll
        for (int n = 0; n < 4; ++n)
          acc[m][n] = __builtin_amdgcn_mfma_f32_16x16x32_bf16(af[m], bfr[n], acc[m][n], 0, 0, 0);
    }
    __syncthreads();
  }

  const int ci = (l >> 4) * 4;
  const int cj = l & 15;
  #pragma unroll
  for (int m = 0; m < 4; ++m) {
    const int i0 = row0 + wr + m * 16 + ci;
    #pragma unroll
    for (int n = 0; n < 4; ++n) {
      const int j = col0 + wc + n * 16 + cj;
      const f32x4 a = acc[m][n];
      #pragma unroll
      for (int r = 0; r < 4; ++r)
        H[(i0 + r) * CCH + j] = (bf16)a[r];
    }
  }
}

// ---- fused GroupNorm: one block per (batch,group); 16ch x 1024px in LDS,
//      stats + normalize + transpose-write hnT[n][c] (bf16) in one pass ----
__global__ __launch_bounds__(256)
void gn_fused(const float* __restrict__ x, const float* __restrict__ gw,
              const float* __restrict__ gb, bf16* __restrict__ hnT)
{
  __shared__ float xs[16 * 1024];   // 64 KB
  __shared__ float red[8];
  const int b = blockIdx.x >> 5;
  const int g = blockIdx.x & 31;
  const float* xp = x + ((long long)b * CCH + g * 16) * NPIX;
  const int t = threadIdx.x;

  float4* xsv = (float4*)xs;
  const float4* gv = (const float4*)xp;
  float s = 0.f, ss = 0.f;
  #pragma unroll
  for (int i = 0; i < 16; ++i) {
    float4 v = gv[t + i * 256];
    xsv[t + i * 256] = v;
    s  += v.x + v.y + v.z + v.w;
    ss += v.x * v.x + v.y * v.y + v.z * v.z + v.w * v.w;
  }
  #pragma unroll
  for (int o = 32; o; o >>= 1) { s += __shfl_xor(s, o); ss += __shfl_xor(ss, o); }
  if ((t & 63) == 0) { red[t >> 6] = s; red[4 + (t >> 6)] = ss; }
  __syncthreads();
  s  = red[0] + red[1] + red[2] + red[3];
  ss = red[4] + red[5] + red[6] + red[7];
  const float mean = s * (1.f / 16384.f);
  const float var  = ss * (1.f / 16384.f) - mean * mean;
  const float rstd = rsqrtf(var + 1e-5f);

  float ac[16], bc[16];
  #pragma unroll
  for (int c = 0; c < 16; ++c) {
    const float wv = gw[g * 16 + c] * rstd;
    ac[c] = wv;
    bc[c] = gb[g * 16 + c] - mean * wv;
  }

  bf16* hp = hnT + (long long)b * CN + g * 16;
  #pragma unroll
  for (int r = 0; r < 4; ++r) {
    const int n = t + r * 256;
    bf16x8 o0, o1;
    #pragma unroll
    for (int c = 0; c < 8; ++c)
      o0[c] = (bf16)(xs[c * 1024 + n] * ac[c] + bc[c]);
    #pragma unroll
    for (int c = 0; c < 8; ++c)
      o1[c] = (bf16)(xs[(8 + c) * 1024 + n] * ac[8 + c] + bc[8 + c]);
    *(bf16x8*)&hp[(long long)n * CCH]     = o0;
    *(bf16x8*)&hp[(long long)n * CCH + 8] = o1;
  }
}

// ---- fp32 -> bf16 weight conversion (once) ----
__global__ __launch_bounds__(256)
void cvt_weights(const float* __restrict__ qw, const float* __restrict__ pw,
                 bf16* __restrict__ qwb, bf16* __restrict__ pwb)
{
  const int i = blockIdx.x * 256 + threadIdx.x;
  if (i < 3 * CCH * CCH) qwb[i] = (bf16)qw[i];
  if (i < CCH * CCH) pwb[i] = (bf16)pw[i];
}

extern "C" void kernel_launch(void* const* d_in, const int* in_sizes, int n_in,
                              void* d_out, int out_size, void* d_ws, size_t ws_size,
                              hipStream_t stream)
{
  const float* x      = (const float*)d_in[0];
  const float* gn_w   = (const float*)d_in[1];
  const float* gn_b   = (const float*)d_in[2];
  const float* qkv_w  = (const float*)d_in[3];
  const float* qkv_b  = (const float*)d_in[4];
  const float* proj_w = (const float*)d_in[5];
  const float* proj_b = (const float*)d_in[6];
  float* out = (float*)d_out;
  (void)in_sizes; (void)n_in; (void)out_size;

  char* ws = (char*)d_ws;
  size_t off = 0;
  auto alloc = [&](size_t bytes) -> char* {
    char* p = ws + off;
    off += (bytes + 255) & ~(size_t)255;
    return p;
  };
  bf16* qkv_wb  = (bf16*)alloc(3 * 512 * 512 * 2);
  bf16* proj_wb = (bf16*)alloc(512 * 512 * 2);
  const size_t fixed = off;
  // per-batch: hnT 1MB + qkT 2MB + v 1MB + scores 4MB + hvT 1MB + pstats 128KB
  const size_t per = 1048576ull + 2097152ull + 1048576ull + 4194304ull
                   + 1048576ull + 131072ull;
  int Bc = 32;
  if (ws_size > fixed) {
    size_t fit = (ws_size - fixed) / per;
    if (fit < 32) Bc = (int)fit;
  } else {
    Bc = 0;
  }
  if (Bc < 1) Bc = 1;

  bf16*  hnT    = (bf16*) alloc((size_t)Bc * 1048576);
  bf16*  qkT    = (bf16*) alloc((size_t)Bc * 2097152);
  bf16*  vbuf   = (bf16*) alloc((size_t)Bc * 1048576);
  float* scores = (float*)alloc((size_t)Bc * 4194304);
  bf16*  hvT    = (bf16*) alloc((size_t)Bc * 1048576);
  float* pstats = (float*)alloc((size_t)Bc * 131072);

  cvt_weights<<<dim3(3072), 256, 0, stream>>>(qkv_w, proj_w, qkv_wb, proj_wb);

  const float scale = 0.044194173824159216f;  // 512^-0.5
  for (int b0 = 0; b0 < 32; b0 += Bc) {
    const int bc = (32 - b0 < Bc) ? (32 - b0) : Bc;
    const float* xb = x + (size_t)b0 * CN;

    gn_fused<<<dim3(bc * 32), 256, 0, stream>>>(xb, gn_w, gn_b, hnT);

    // QKV: [n][o] = hnT[n][c] . qkv_w[o][c];  q,k -> qkT, v -> vbuf[c][m]
    gemm_bt<0><<<dim3(8, 12, bc), 256, 0, stream>>>(
        hnT, 512, 524288, qkv_wb, 512, 0,
        (char*)qkT, 2097152, (char*)vbuf, 1048576, qkv_b, nullptr, nullptr,
        512, 1.f);

    // scores[n][m] = q[n] . k[m] (fp32 * scale) + partial softmax stats
    gemm_bt<1><<<dim3(8, 8, bc), 256, 0, stream>>>(
        qkT, 1024, 1048576, qkT + 512, 1024, 1048576,
        (char*)scores, 4194304, nullptr, 0, nullptr, nullptr, pstats,
        512, scale);

    // hvT[n][c] = softmax(S)[n][:] . v[c][:]  (fused exp staging)
    pv_fused<<<dim3(8, 4, bc), 256, 0, stream>>>(
        scores, 1048576, pstats, 32768, vbuf, 524288, hvT, 524288);

    // out[c][n] = proj_w[c][:] . hvT[n][:] + proj_b[c] + x[c][n]
    gemm_bt<3><<<dim3(4, 8, bc), 256, 0, stream>>>(
        proj_wb, 512, 0, hvT, 512, 524288,
        (char*)(out + (size_t)b0 * CN), 2097152, nullptr, 0, proj_b, xb,
        nullptr, 512, 1.f);
  }
}

// Round 8
// 266.601 us; speedup vs baseline: 1.5366x; 1.5366x over previous
//
#include <hip/hip_runtime.h>
#include <stdint.h>

typedef __bf16 bf16;
typedef __bf16 bf16x4 __attribute__((ext_vector_type(4)));
typedef __bf16 bf16x8 __attribute__((ext_vector_type(8)));
typedef float f32x4 __attribute__((ext_vector_type(4)));

#define CN 524288    // C*N = 512*1024 (per-batch x elements)
#define NPIX 1024
#define CCH 512

// ---- async global->LDS, 16B per lane ----
__device__ __forceinline__ void gload_lds16(const void* g, void* l) {
  auto gp = reinterpret_cast<const __attribute__((address_space(1))) uint32_t*>(
      reinterpret_cast<uintptr_t>(g));
  auto lp = reinterpret_cast<__attribute__((address_space(3))) uint32_t*>(
      static_cast<uint32_t>(reinterpret_cast<uintptr_t>(l)));
  __builtin_amdgcn_global_load_lds(gp, lp, 16, 0, 0);
}

// ======================================================================
// gemm_bt: C[i,j] = sum_k A[i,k] * Bt[j,k]   (known-best engine, 357us cfg)
// 256x256 tile, BK=64, 8 waves (512 thr, 2Mx4N -> 128x64 per wave),
// double-buffered LDS (128 KB), counted-vmcnt pipeline, 16x16x32 bf16
// MFMA, verified seg-XOR swizzle (0 bank conflicts on HW).
// EPI 0: QKV   (bias; j<1024 -> qkT[i][j], else v[j-1024][i])
// EPI 1: scores (bf16 out = S*scale, ld=1024)
// EPI 2: PV    (bf16 out, ld=512)
// EPI 3: proj  (fp32 out + proj_b[i] + resid)
// ======================================================================
template<int EPI>
__global__ __launch_bounds__(512, 2)
void gemm_bt(const bf16* __restrict__ A, int lda, long long sA,
             const bf16* __restrict__ Bt, int ldb, long long sB,
             char* __restrict__ Cp, long long sC,
             char* __restrict__ C2p, long long sC2,
             const float* __restrict__ bias,
             const float* __restrict__ resid,
             int K, float scale)
{
  __shared__ __align__(16) bf16 As[2 * 16384];   // 2 x [256][64]
  __shared__ __align__(16) bf16 Bs[2 * 16384];
  const int t = threadIdx.x;
  const int w = t >> 6;
  const int l = t & 63;
  const int z = blockIdx.z;
  A  += (long long)z * sA;
  Bt += (long long)z * sB;
  Cp += (long long)z * sC;
  if (C2p) C2p += (long long)z * sC2;
  const float* residb = (EPI == 3) ? (resid + (long long)z * CN) : nullptr;

  const int row0 = blockIdx.x * 256;
  const int col0 = blockIdx.y * 256;
  const int wr = w >> 2;              // 0..1 : wave row group (128 rows)
  const int wc = w & 3;               // 0..3 : wave col group (64 cols)

  f32x4 acc[8][4] = {};

  // ---- staging geometry: chunk = 64 rows x 64 cols bf16 = 8KB ----
  const int wv  = w;                  // wave id 0..7
  const int srow = (l >> 3);          // 0..7 row within wave's 8-row slice
  const int segp = ((l & 7) ^ srow) << 3;   // pre-swizzled k-seg (elements)
  const bf16* baseA = A  + (long long)(row0 + wv * 8 + srow) * lda + segp;
  const bf16* baseB = Bt + (long long)(col0 + wv * 8 + srow) * ldb + segp;

  auto stageA = [&](int kt1, int buf, int c) {
    gload_lds16(baseA + (long long)c * 64 * lda + kt1 * 64,
                &As[buf * 16384 + c * 4096 + wv * 512]);
  };
  auto stageB = [&](int kt1, int buf, int c) {
    gload_lds16(baseB + (long long)c * 64 * ldb + kt1 * 64,
                &Bs[buf * 16384 + c * 4096 + wv * 512]);
  };

  // ---- fragment-read geometry ----
  const int lrow = l & 15;
  const int lx = l & 7;
  const int s0 = (((l >> 4)) ^ lx) << 3;       // kk=0 swizzled seg offset
  const int s1 = (((l >> 4) + 4) ^ lx) << 3;   // kk=1

  const int nt = K >> 6;

  // prologue: tile 0 -> buf 0
  #pragma unroll
  for (int c = 0; c < 4; ++c) stageB(0, 0, c);
  #pragma unroll
  for (int c = 0; c < 4; ++c) stageA(0, 0, c);

  #pragma unroll 1
  for (int kt = 0; kt < nt; ++kt) {
    const int cur = kt & 1, nxt = cur ^ 1;
    const bool pf = (kt + 1) < nt;
    if (pf) {
      #pragma unroll
      for (int c = 0; c < 4; ++c) stageB(kt + 1, nxt, c);
      asm volatile("s_waitcnt vmcnt(4)" ::: "memory");
    } else {
      asm volatile("s_waitcnt vmcnt(0)" ::: "memory");
    }
    __builtin_amdgcn_sched_barrier(0);
    __builtin_amdgcn_s_barrier();
    asm volatile("" ::: "memory");

    const int ca = cur * 16384;
    bf16x8 bF0[4], bF1[4], aF0[4], aF1[4];
    #pragma unroll
    for (int nf = 0; nf < 4; ++nf) {
      const int r = wc * 64 + nf * 16 + lrow;
      bF0[nf] = *(const bf16x8*)&Bs[ca + r * 64 + s0];
      bF1[nf] = *(const bf16x8*)&Bs[ca + r * 64 + s1];
    }
    #pragma unroll
    for (int mf = 0; mf < 4; ++mf) {
      const int r = wr * 128 + mf * 16 + lrow;
      aF0[mf] = *(const bf16x8*)&As[ca + r * 64 + s0];
      aF1[mf] = *(const bf16x8*)&As[ca + r * 64 + s1];
    }
    __builtin_amdgcn_s_setprio(1);
    #pragma unroll
    for (int mf = 0; mf < 4; ++mf)
      #pragma unroll
      for (int nf = 0; nf < 4; ++nf)
        acc[mf][nf] = __builtin_amdgcn_mfma_f32_16x16x32_bf16(
            aF1[mf], bF1[nf],
            __builtin_amdgcn_mfma_f32_16x16x32_bf16(aF0[mf], bF0[nf], acc[mf][nf], 0, 0, 0),
            0, 0, 0);
    __builtin_amdgcn_s_setprio(0);
    if (pf) {
      #pragma unroll
      for (int c = 0; c < 4; ++c) stageA(kt + 1, nxt, c);
    }
    #pragma unroll
    for (int mf = 0; mf < 4; ++mf) {
      const int r = wr * 128 + 64 + mf * 16 + lrow;
      aF0[mf] = *(const bf16x8*)&As[ca + r * 64 + s0];
      aF1[mf] = *(const bf16x8*)&As[ca + r * 64 + s1];
    }
    __builtin_amdgcn_s_setprio(1);
    #pragma unroll
    for (int mf = 0; mf < 4; ++mf)
      #pragma unroll
      for (int nf = 0; nf < 4; ++nf)
        acc[4 + mf][nf] = __builtin_amdgcn_mfma_f32_16x16x32_bf16(
            aF1[mf], bF1[nf],
            __builtin_amdgcn_mfma_f32_16x16x32_bf16(aF0[mf], bF0[nf], acc[4 + mf][nf], 0, 0, 0),
            0, 0, 0);
    __builtin_amdgcn_s_setprio(0);
    asm volatile("" ::: "memory");
    __builtin_amdgcn_sched_barrier(0);
    __builtin_amdgcn_s_barrier();
  }

  (void)scale;
  const int ci = (l >> 4) * 4;
  const int cj = l & 15;
  #pragma unroll
  for (int mf = 0; mf < 8; ++mf) {
    const int i0 = row0 + wr * 128 + mf * 16 + ci;
    #pragma unroll
    for (int nf = 0; nf < 4; ++nf) {
      const int j = col0 + wc * 64 + nf * 16 + cj;
      const f32x4 a = acc[mf][nf];
      if constexpr (EPI == 0) {
        const float bj = bias[j];
        if (j < NPIX) {
          bf16* q = (bf16*)Cp;
          #pragma unroll
          for (int r = 0; r < 4; ++r)
            q[(i0 + r) * NPIX + j] = (bf16)(a[r] + bj);
        } else {
          bf16* vb = (bf16*)C2p;
          #pragma unroll
          for (int r = 0; r < 4; ++r)
            vb[(j - NPIX) * NPIX + (i0 + r)] = (bf16)(a[r] + bj);
        }
      } else if constexpr (EPI == 1) {
        bf16* sp = (bf16*)Cp;
        #pragma unroll
        for (int r = 0; r < 4; ++r)
          sp[(i0 + r) * NPIX + j] = (bf16)(a[r] * scale);
      } else if constexpr (EPI == 2) {
        bf16* hp = (bf16*)Cp;
        #pragma unroll
        for (int r = 0; r < 4; ++r)
          hp[(i0 + r) * CCH + j] = (bf16)a[r];
      } else {
        float* op = (float*)Cp;
        #pragma unroll
        for (int r = 0; r < 4; ++r)
          op[(i0 + r) * NPIX + j] = a[r] + bias[i0 + r] + residb[(i0 + r) * NPIX + j];
      }
    }
  }
}

// ---- fused GroupNorm: one block per (batch,group); 16ch x 1024px in LDS,
//      stats + normalize + transpose-write hnT[n][c] (bf16) in one pass ----
__global__ __launch_bounds__(256)
void gn_fused(const float* __restrict__ x, const float* __restrict__ gw,
              const float* __restrict__ gb, bf16* __restrict__ hnT)
{
  __shared__ float xs[16 * 1024];   // 64 KB
  __shared__ float red[8];
  const int b = blockIdx.x >> 5;
  const int g = blockIdx.x & 31;
  const float* xp = x + ((long long)b * CCH + g * 16) * NPIX;
  const int t = threadIdx.x;

  float4* xsv = (float4*)xs;
  const float4* gv = (const float4*)xp;
  float s = 0.f, ss = 0.f;
  #pragma unroll
  for (int i = 0; i < 16; ++i) {
    float4 v = gv[t + i * 256];
    xsv[t + i * 256] = v;
    s  += v.x + v.y + v.z + v.w;
    ss += v.x * v.x + v.y * v.y + v.z * v.z + v.w * v.w;
  }
  #pragma unroll
  for (int o = 32; o; o >>= 1) { s += __shfl_xor(s, o); ss += __shfl_xor(ss, o); }
  if ((t & 63) == 0) { red[t >> 6] = s; red[4 + (t >> 6)] = ss; }
  __syncthreads();
  s  = red[0] + red[1] + red[2] + red[3];
  ss = red[4] + red[5] + red[6] + red[7];
  const float mean = s * (1.f / 16384.f);
  const float var  = ss * (1.f / 16384.f) - mean * mean;
  const float rstd = rsqrtf(var + 1e-5f);

  float ac[16], bc[16];
  #pragma unroll
  for (int c = 0; c < 16; ++c) {
    const float wv = gw[g * 16 + c] * rstd;
    ac[c] = wv;
    bc[c] = gb[g * 16 + c] - mean * wv;
  }

  bf16* hp = hnT + (long long)b * CN + g * 16;
  #pragma unroll
  for (int r = 0; r < 4; ++r) {
    const int n = t + r * 256;
    bf16x8 o0, o1;
    #pragma unroll
    for (int c = 0; c < 8; ++c)
      o0[c] = (bf16)(xs[c * 1024 + n] * ac[c] + bc[c]);
    #pragma unroll
    for (int c = 0; c < 8; ++c)
      o1[c] = (bf16)(xs[(8 + c) * 1024 + n] * ac[8 + c] + bc[8 + c]);
    *(bf16x8*)&hp[(long long)n * CCH]     = o0;
    *(bf16x8*)&hp[(long long)n * CCH + 8] = o1;
  }
}

// ---- row softmax over 1024 bf16, in place (row = 2KB) ----
__global__ __launch_bounds__(256)
void softmax_rows(bf16* __restrict__ scores)
{
  bf16* p = scores + (long long)blockIdx.x * NPIX;
  const int t = threadIdx.x;
  const bf16x4 v = *(const bf16x4*)(p + t * 4);
  float f0 = (float)v[0], f1 = (float)v[1], f2 = (float)v[2], f3 = (float)v[3];
  float m = fmaxf(fmaxf(f0, f1), fmaxf(f2, f3));
  #pragma unroll
  for (int o = 32; o; o >>= 1) m = fmaxf(m, __shfl_xor(m, o));
  __shared__ float red[4];
  if ((t & 63) == 0) red[t >> 6] = m;
  __syncthreads();
  m = fmaxf(fmaxf(red[0], red[1]), fmaxf(red[2], red[3]));
  const float e0 = __expf(f0 - m), e1 = __expf(f1 - m);
  const float e2 = __expf(f2 - m), e3 = __expf(f3 - m);
  float s = e0 + e1 + e2 + e3;
  #pragma unroll
  for (int o = 32; o; o >>= 1) s += __shfl_xor(s, o);
  __syncthreads();
  if ((t & 63) == 0) red[t >> 6] = s;
  __syncthreads();
  s = red[0] + red[1] + red[2] + red[3];
  const float inv = 1.f / s;
  bf16x4 ov;
  ov[0] = (bf16)(e0 * inv); ov[1] = (bf16)(e1 * inv);
  ov[2] = (bf16)(e2 * inv); ov[3] = (bf16)(e3 * inv);
  *(bf16x4*)(p + t * 4) = ov;
}

// ---- fp32 -> bf16 weight conversion (once) ----
__global__ __launch_bounds__(256)
void cvt_weights(const float* __restrict__ qw, const float* __restrict__ pw,
                 bf16* __restrict__ qwb, bf16* __restrict__ pwb)
{
  const int i = blockIdx.x * 256 + threadIdx.x;
  if (i < 3 * CCH * CCH) qwb[i] = (bf16)qw[i];
  if (i < CCH * CCH) pwb[i] = (bf16)pw[i];
}

extern "C" void kernel_launch(void* const* d_in, const int* in_sizes, int n_in,
                              void* d_out, int out_size, void* d_ws, size_t ws_size,
                              hipStream_t stream)
{
  const float* x      = (const float*)d_in[0];
  const float* gn_w   = (const float*)d_in[1];
  const float* gn_b   = (const float*)d_in[2];
  const float* qkv_w  = (const float*)d_in[3];
  const float* qkv_b  = (const float*)d_in[4];
  const float* proj_w = (const float*)d_in[5];
  const float* proj_b = (const float*)d_in[6];
  float* out = (float*)d_out;
  (void)in_sizes; (void)n_in; (void)out_size;

  char* ws = (char*)d_ws;
  size_t off = 0;
  auto alloc = [&](size_t bytes) -> char* {
    char* p = ws + off;
    off += (bytes + 255) & ~(size_t)255;
    return p;
  };
  bf16* qkv_wb  = (bf16*)alloc(3 * 512 * 512 * 2);
  bf16* proj_wb = (bf16*)alloc(512 * 512 * 2);
  const size_t fixed = off;
  // per-batch: hnT 1MB + qkT 2MB + v 1MB + scores(bf16) 2MB + hvT 1MB
  const size_t per = 1048576ull + 2097152ull + 1048576ull + 2097152ull + 1048576ull;
  int Bc = 32;
  if (ws_size > fixed) {
    size_t fit = (ws_size - fixed) / per;
    if (fit < 32) Bc = (int)fit;
  } else {
    Bc = 0;
  }
  if (Bc < 1) Bc = 1;

  bf16*  hnT    = (bf16*) alloc((size_t)Bc * 1048576);
  bf16*  qkT    = (bf16*) alloc((size_t)Bc * 2097152);
  bf16*  vbuf   = (bf16*) alloc((size_t)Bc * 1048576);
  bf16*  scores = (bf16*) alloc((size_t)Bc * 2097152);
  bf16*  hvT    = (bf16*) alloc((size_t)Bc * 1048576);

  cvt_weights<<<dim3(3072), 256, 0, stream>>>(qkv_w, proj_w, qkv_wb, proj_wb);

  const float scale = 0.044194173824159216f;  // 512^-0.5
  for (int b0 = 0; b0 < 32; b0 += Bc) {
    const int bc = (32 - b0 < Bc) ? (32 - b0) : Bc;
    const float* xb = x + (size_t)b0 * CN;

    gn_fused<<<dim3(bc * 32), 256, 0, stream>>>(xb, gn_w, gn_b, hnT);

    // QKV: [n][o] = hnT[n][c] . qkv_w[o][c];  q,k -> qkT[n][0..1023], v -> vbuf[c][m]
    gemm_bt<0><<<dim3(4, 6, bc), 512, 0, stream>>>(
        hnT, 512, 524288, qkv_wb, 512, 0,
        (char*)qkT, 2097152, (char*)vbuf, 1048576, qkv_b, nullptr, 512, 1.f);

    // scores[n][m] = q[n][:] . k[m][:]  (bf16 out, *scale)
    gemm_bt<1><<<dim3(4, 4, bc), 512, 0, stream>>>(
        qkT, 1024, 1048576, qkT + 512, 1024, 1048576,
        (char*)scores, 2097152, nullptr, 0, nullptr, nullptr, 512, scale);

    softmax_rows<<<dim3(bc * 1024), 256, 0, stream>>>(scores);

    // hvT[n][c] = attn[n][m] . v[c][m]   (attn bf16 dense, lda=1024)
    gemm_bt<2><<<dim3(4, 2, bc), 512, 0, stream>>>(
        scores, 1024, 1048576, vbuf, 1024, 524288,
        (char*)hvT, 1048576, nullptr, 0, nullptr, nullptr, 1024, 1.f);

    // out[c][n] = proj_w[c][:] . hvT[n][:] + proj_b[c] + x[c][n]
    gemm_bt<3><<<dim3(2, 4, bc), 512, 0, stream>>>(
        proj_wb, 512, 0, hvT, 512, 524288,
        (char*)(out + (size_t)b0 * CN), 2097152, nullptr, 0, proj_b, xb, 512, 1.f);
  }
}

// Round 9
// 245.138 us; speedup vs baseline: 1.6712x; 1.0876x over previous
//
#include <hip/hip_runtime.h>
#include <stdint.h>

typedef __bf16 bf16;
typedef __bf16 bf16x4 __attribute__((ext_vector_type(4)));
typedef __bf16 bf16x8 __attribute__((ext_vector_type(8)));
typedef float f32x4 __attribute__((ext_vector_type(4)));

#define CN 524288    // C*N = 512*1024 (per-batch x elements)
#define NPIX 1024
#define CCH 512

// ---- async global->LDS, 16B per lane ----
__device__ __forceinline__ void gload_lds16(const void* g, void* l) {
  auto gp = reinterpret_cast<const __attribute__((address_space(1))) uint32_t*>(
      reinterpret_cast<uintptr_t>(g));
  auto lp = reinterpret_cast<__attribute__((address_space(3))) uint32_t*>(
      static_cast<uint32_t>(reinterpret_cast<uintptr_t>(l)));
  __builtin_amdgcn_global_load_lds(gp, lp, 16, 0, 0);
}

// ======================================================================
// gemm_bt: C[i,j] = sum_k A[i,k] * Bt[j,k]   (known-best engine)
// 256x256 tile, BK=64, 8 waves (512 thr, 2Mx4N -> 128x64 per wave),
// double-buffered LDS (128 KB), counted-vmcnt pipeline, 16x16x32 bf16
// MFMA, verified seg-XOR swizzle (0 bank conflicts on HW).
// EPI 0: QKV   (bias; j<1024 -> qkT[i][j], else v[j-1024][i])
// EPI 1: U = exp(S*scale) bf16 (ld=1024) + per-block partial row-sums
//        -> pst[(z*4+by)*1024 + row]  (deterministic, no atomics)
// EPI 2: PV    (bf16 out = acc / rowsum, ld=512; rowsum = sum of 4 pst)
// EPI 3: proj  (fp32 out + proj_b[i] + resid)
// ======================================================================
template<int EPI>
__global__ __launch_bounds__(512, 2)
void gemm_bt(const bf16* __restrict__ A, int lda, long long sA,
             const bf16* __restrict__ Bt, int ldb, long long sB,
             char* __restrict__ Cp, long long sC,
             char* __restrict__ C2p, long long sC2,
             const float* __restrict__ bias,
             const float* __restrict__ resid,
             float* __restrict__ pst,
             int K, float scale)
{
  __shared__ __align__(16) bf16 As[2 * 16384];   // 2 x [256][64]
  __shared__ __align__(16) bf16 Bs[2 * 16384];
  const int t = threadIdx.x;
  const int w = t >> 6;
  const int l = t & 63;
  const int z = blockIdx.z;
  A  += (long long)z * sA;
  Bt += (long long)z * sB;
  Cp += (long long)z * sC;
  if (C2p) C2p += (long long)z * sC2;
  const float* residb = (EPI == 3) ? (resid + (long long)z * CN) : nullptr;

  const int row0 = blockIdx.x * 256;
  const int col0 = blockIdx.y * 256;
  const int wr = w >> 2;              // 0..1 : wave row group (128 rows)
  const int wc = w & 3;               // 0..3 : wave col group (64 cols)

  f32x4 acc[8][4] = {};

  // ---- staging geometry: chunk = 64 rows x 64 cols bf16 = 8KB ----
  const int wv  = w;                  // wave id 0..7
  const int srow = (l >> 3);          // 0..7 row within wave's 8-row slice
  const int segp = ((l & 7) ^ srow) << 3;   // pre-swizzled k-seg (elements)
  const bf16* baseA = A  + (long long)(row0 + wv * 8 + srow) * lda + segp;
  const bf16* baseB = Bt + (long long)(col0 + wv * 8 + srow) * ldb + segp;

  auto stageA = [&](int kt1, int buf, int c) {
    gload_lds16(baseA + (long long)c * 64 * lda + kt1 * 64,
                &As[buf * 16384 + c * 4096 + wv * 512]);
  };
  auto stageB = [&](int kt1, int buf, int c) {
    gload_lds16(baseB + (long long)c * 64 * ldb + kt1 * 64,
                &Bs[buf * 16384 + c * 4096 + wv * 512]);
  };

  // ---- fragment-read geometry ----
  const int lrow = l & 15;
  const int lx = l & 7;
  const int s0 = (((l >> 4)) ^ lx) << 3;       // kk=0 swizzled seg offset
  const int s1 = (((l >> 4) + 4) ^ lx) << 3;   // kk=1

  const int nt = K >> 6;

  // prologue: tile 0 -> buf 0
  #pragma unroll
  for (int c = 0; c < 4; ++c) stageB(0, 0, c);
  #pragma unroll
  for (int c = 0; c < 4; ++c) stageA(0, 0, c);

  #pragma unroll 1
  for (int kt = 0; kt < nt; ++kt) {
    const int cur = kt & 1, nxt = cur ^ 1;
    const bool pf = (kt + 1) < nt;
    if (pf) {
      #pragma unroll
      for (int c = 0; c < 4; ++c) stageB(kt + 1, nxt, c);
      asm volatile("s_waitcnt vmcnt(4)" ::: "memory");
    } else {
      asm volatile("s_waitcnt vmcnt(0)" ::: "memory");
    }
    __builtin_amdgcn_sched_barrier(0);
    __builtin_amdgcn_s_barrier();
    asm volatile("" ::: "memory");

    const int ca = cur * 16384;
    bf16x8 bF0[4], bF1[4], aF0[4], aF1[4];
    #pragma unroll
    for (int nf = 0; nf < 4; ++nf) {
      const int r = wc * 64 + nf * 16 + lrow;
      bF0[nf] = *(const bf16x8*)&Bs[ca + r * 64 + s0];
      bF1[nf] = *(const bf16x8*)&Bs[ca + r * 64 + s1];
    }
    #pragma unroll
    for (int mf = 0; mf < 4; ++mf) {
      const int r = wr * 128 + mf * 16 + lrow;
      aF0[mf] = *(const bf16x8*)&As[ca + r * 64 + s0];
      aF1[mf] = *(const bf16x8*)&As[ca + r * 64 + s1];
    }
    __builtin_amdgcn_s_setprio(1);
    #pragma unroll
    for (int mf = 0; mf < 4; ++mf)
      #pragma unroll
      for (int nf = 0; nf < 4; ++nf)
        acc[mf][nf] = __builtin_amdgcn_mfma_f32_16x16x32_bf16(
            aF1[mf], bF1[nf],
            __builtin_amdgcn_mfma_f32_16x16x32_bf16(aF0[mf], bF0[nf], acc[mf][nf], 0, 0, 0),
            0, 0, 0);
    __builtin_amdgcn_s_setprio(0);
    if (pf) {
      #pragma unroll
      for (int c = 0; c < 4; ++c) stageA(kt + 1, nxt, c);
    }
    #pragma unroll
    for (int mf = 0; mf < 4; ++mf) {
      const int r = wr * 128 + 64 + mf * 16 + lrow;
      aF0[mf] = *(const bf16x8*)&As[ca + r * 64 + s0];
      aF1[mf] = *(const bf16x8*)&As[ca + r * 64 + s1];
    }
    __builtin_amdgcn_s_setprio(1);
    #pragma unroll
    for (int mf = 0; mf < 4; ++mf)
      #pragma unroll
      for (int nf = 0; nf < 4; ++nf)
        acc[4 + mf][nf] = __builtin_amdgcn_mfma_f32_16x16x32_bf16(
            aF1[mf], bF1[nf],
            __builtin_amdgcn_mfma_f32_16x16x32_bf16(aF0[mf], bF0[nf], acc[4 + mf][nf], 0, 0, 0),
            0, 0, 0);
    __builtin_amdgcn_s_setprio(0);
    asm volatile("" ::: "memory");
    __builtin_amdgcn_sched_barrier(0);
    __builtin_amdgcn_s_barrier();
  }

  const int ci = (l >> 4) * 4;
  const int cj = l & 15;

  if constexpr (EPI == 1) {
    // ---- U = exp(acc*scale) + deterministic partial row-sums ----
    bf16* sp = (bf16*)Cp;
    float* part = (float*)As;          // reuse LDS: part[wc*256 + localrow]
    #pragma unroll
    for (int mf = 0; mf < 8; ++mf) {
      const int lr0 = wr * 128 + mf * 16 + ci;   // tile-local row
      #pragma unroll
      for (int r = 0; r < 4; ++r) {
        float s = 0.f;
        #pragma unroll
        for (int nf = 0; nf < 4; ++nf) {
          const int j = col0 + wc * 64 + nf * 16 + cj;
          const float u = __expf(acc[mf][nf][r] * scale);
          const bf16 ub = (bf16)u;
          sp[(row0 + lr0 + r) * NPIX + j] = ub;
          s += (float)ub;
        }
        s += __shfl_xor(s, 1); s += __shfl_xor(s, 2);
        s += __shfl_xor(s, 4); s += __shfl_xor(s, 8);
        if (cj == 0) part[wc * 256 + lr0 + r] = s;
      }
    }
    __syncthreads();
    if (t < 256)
      pst[((long long)z * 4 + blockIdx.y) * 1024 + row0 + t]
          = part[t] + part[256 + t] + part[512 + t] + part[768 + t];
    return;
  }

  #pragma unroll
  for (int mf = 0; mf < 8; ++mf) {
    const int i0 = row0 + wr * 128 + mf * 16 + ci;
    if constexpr (EPI == 2) {
      const float* pz = pst + (long long)z * 4096;
      #pragma unroll
      for (int r = 0; r < 4; ++r) {
        const int row = i0 + r;
        const float is = 1.f / (pz[row] + pz[1024 + row] +
                                pz[2048 + row] + pz[3072 + row]);
        bf16* hp = (bf16*)Cp;
        #pragma unroll
        for (int nf = 0; nf < 4; ++nf) {
          const int j = col0 + wc * 64 + nf * 16 + cj;
          hp[row * CCH + j] = (bf16)(acc[mf][nf][r] * is);
        }
      }
    } else {
      #pragma unroll
      for (int nf = 0; nf < 4; ++nf) {
        const int j = col0 + wc * 64 + nf * 16 + cj;
        const f32x4 a = acc[mf][nf];
        if constexpr (EPI == 0) {
          const float bj = bias[j];
          if (j < NPIX) {
            bf16* q = (bf16*)Cp;
            #pragma unroll
            for (int r = 0; r < 4; ++r)
              q[(i0 + r) * NPIX + j] = (bf16)(a[r] + bj);
          } else {
            bf16* vb = (bf16*)C2p;
            #pragma unroll
            for (int r = 0; r < 4; ++r)
              vb[(j - NPIX) * NPIX + (i0 + r)] = (bf16)(a[r] + bj);
          }
        } else {
          float* op = (float*)Cp;
          #pragma unroll
          for (int r = 0; r < 4; ++r)
            op[(i0 + r) * NPIX + j] = a[r] + bias[i0 + r] + residb[(i0 + r) * NPIX + j];
        }
      }
    }
  }
}

// ---- fused GroupNorm: one block per (batch,group); 16ch x 1024px in LDS,
//      stats + normalize + transpose-write hnT[n][c] (bf16) in one pass ----
__global__ __launch_bounds__(256)
void gn_fused(const float* __restrict__ x, const float* __restrict__ gw,
              const float* __restrict__ gb, bf16* __restrict__ hnT)
{
  __shared__ float xs[16 * 1024];   // 64 KB
  __shared__ float red[8];
  const int b = blockIdx.x >> 5;
  const int g = blockIdx.x & 31;
  const float* xp = x + ((long long)b * CCH + g * 16) * NPIX;
  const int t = threadIdx.x;

  float4* xsv = (float4*)xs;
  const float4* gv = (const float4*)xp;
  float s = 0.f, ss = 0.f;
  #pragma unroll
  for (int i = 0; i < 16; ++i) {
    float4 v = gv[t + i * 256];
    xsv[t + i * 256] = v;
    s  += v.x + v.y + v.z + v.w;
    ss += v.x * v.x + v.y * v.y + v.z * v.z + v.w * v.w;
  }
  #pragma unroll
  for (int o = 32; o; o >>= 1) { s += __shfl_xor(s, o); ss += __shfl_xor(ss, o); }
  if ((t & 63) == 0) { red[t >> 6] = s; red[4 + (t >> 6)] = ss; }
  __syncthreads();
  s  = red[0] + red[1] + red[2] + red[3];
  ss = red[4] + red[5] + red[6] + red[7];
  const float mean = s * (1.f / 16384.f);
  const float var  = ss * (1.f / 16384.f) - mean * mean;
  const float rstd = rsqrtf(var + 1e-5f);

  float ac[16], bc[16];
  #pragma unroll
  for (int c = 0; c < 16; ++c) {
    const float wv = gw[g * 16 + c] * rstd;
    ac[c] = wv;
    bc[c] = gb[g * 16 + c] - mean * wv;
  }

  bf16* hp = hnT + (long long)b * CN + g * 16;
  #pragma unroll
  for (int r = 0; r < 4; ++r) {
    const int n = t + r * 256;
    bf16x8 o0, o1;
    #pragma unroll
    for (int c = 0; c < 8; ++c)
      o0[c] = (bf16)(xs[c * 1024 + n] * ac[c] + bc[c]);
    #pragma unroll
    for (int c = 0; c < 8; ++c)
      o1[c] = (bf16)(xs[(8 + c) * 1024 + n] * ac[8 + c] + bc[8 + c]);
    *(bf16x8*)&hp[(long long)n * CCH]     = o0;
    *(bf16x8*)&hp[(long long)n * CCH + 8] = o1;
  }
}

// ---- fp32 -> bf16 weight conversion (once) ----
__global__ __launch_bounds__(256)
void cvt_weights(const float* __restrict__ qw, const float* __restrict__ pw,
                 bf16* __restrict__ qwb, bf16* __restrict__ pwb)
{
  const int i = blockIdx.x * 256 + threadIdx.x;
  if (i < 3 * CCH * CCH) qwb[i] = (bf16)qw[i];
  if (i < CCH * CCH) pwb[i] = (bf16)pw[i];
}

extern "C" void kernel_launch(void* const* d_in, const int* in_sizes, int n_in,
                              void* d_out, int out_size, void* d_ws, size_t ws_size,
                              hipStream_t stream)
{
  const float* x      = (const float*)d_in[0];
  const float* gn_w   = (const float*)d_in[1];
  const float* gn_b   = (const float*)d_in[2];
  const float* qkv_w  = (const float*)d_in[3];
  const float* qkv_b  = (const float*)d_in[4];
  const float* proj_w = (const float*)d_in[5];
  const float* proj_b = (const float*)d_in[6];
  float* out = (float*)d_out;
  (void)in_sizes; (void)n_in; (void)out_size;

  char* ws = (char*)d_ws;
  size_t off = 0;
  auto alloc = [&](size_t bytes) -> char* {
    char* p = ws + off;
    off += (bytes + 255) & ~(size_t)255;
    return p;
  };
  bf16* qkv_wb  = (bf16*)alloc(3 * 512 * 512 * 2);
  bf16* proj_wb = (bf16*)alloc(512 * 512 * 2);
  const size_t fixed = off;
  // per-batch: hnT 1MB + qkT 2MB + v 1MB + U(bf16) 2MB + hvT 1MB + pst 16KB
  const size_t per = 1048576ull + 2097152ull + 1048576ull + 2097152ull
                   + 1048576ull + 16384ull;
  int Bc = 32;
  if (ws_size > fixed) {
    size_t fit = (ws_size - fixed) / per;
    if (fit < 32) Bc = (int)fit;
  } else {
    Bc = 0;
  }
  if (Bc < 1) Bc = 1;

  bf16*  hnT    = (bf16*) alloc((size_t)Bc * 1048576);
  bf16*  qkT    = (bf16*) alloc((size_t)Bc * 2097152);
  bf16*  vbuf   = (bf16*) alloc((size_t)Bc * 1048576);
  bf16*  ubuf   = (bf16*) alloc((size_t)Bc * 2097152);
  bf16*  hvT    = (bf16*) alloc((size_t)Bc * 1048576);
  float* pstats = (float*)alloc((size_t)Bc * 16384);

  cvt_weights<<<dim3(3072), 256, 0, stream>>>(qkv_w, proj_w, qkv_wb, proj_wb);

  const float scale = 0.044194173824159216f;  // 512^-0.5
  for (int b0 = 0; b0 < 32; b0 += Bc) {
    const int bc = (32 - b0 < Bc) ? (32 - b0) : Bc;
    const float* xb = x + (size_t)b0 * CN;

    gn_fused<<<dim3(bc * 32), 256, 0, stream>>>(xb, gn_w, gn_b, hnT);

    // QKV: [n][o] = hnT[n][c] . qkv_w[o][c];  q,k -> qkT[n][0..1023], v -> vbuf[c][m]
    gemm_bt<0><<<dim3(4, 6, bc), 512, 0, stream>>>(
        hnT, 512, 524288, qkv_wb, 512, 0,
        (char*)qkT, 2097152, (char*)vbuf, 1048576, qkv_b, nullptr, nullptr,
        512, 1.f);

    // U[n][m] = exp(q[n].k[m] * scale)  (bf16) + partial row sums -> pstats
    gemm_bt<1><<<dim3(4, 4, bc), 512, 0, stream>>>(
        qkT, 1024, 1048576, qkT + 512, 1024, 1048576,
        (char*)ubuf, 2097152, nullptr, 0, nullptr, nullptr, pstats,
        512, scale);

    // hvT[n][c] = (U[n][:] . v[c][:]) / rowsum[n]
    gemm_bt<2><<<dim3(4, 2, bc), 512, 0, stream>>>(
        ubuf, 1024, 1048576, vbuf, 1024, 524288,
        (char*)hvT, 1048576, nullptr, 0, nullptr, nullptr, pstats,
        1024, 1.f);

    // out[c][n] = proj_w[c][:] . hvT[n][:] + proj_b[c] + x[c][n]
    gemm_bt<3><<<dim3(2, 4, bc), 512, 0, stream>>>(
        proj_wb, 512, 0, hvT, 512, 524288,
        (char*)(out + (size_t)b0 * CN), 2097152, nullptr, 0, proj_b, xb,
        nullptr, 512, 1.f);
  }
}